// Round 1
// 408.768 us; speedup vs baseline: 1.0240x; 1.0240x over previous
//
#include <hip/hip_runtime.h>
#include <math.h>

#define ROW 2064   // 6*344 floats per obs row
#define OS  344

typedef _Float16 h2 __attribute__((ext_vector_type(2)));
typedef _Float16 h8 __attribute__((ext_vector_type(8)));

// fp16 weight blob layout (offsets in f16 units), identical to round 3.
#define OFF_EGO 0        // 128 x 24
#define OFF_DYN 3072     // 64 x 128
#define OFF_L1  11264    // 64 x 112
#define OFF_L2  18432    // 64 x 64
#define OFF_WHX 22528    // 2 x 48 x 4
#define OFF_WO  22912    // 2 x 64 x 48
#define OFF_W1  29056    // 64 x 288 (k: ef64, hdv64, cav64, lane64, span[224..256))
#define OFF_W2  47488    // 64 x 64
#define WT_F16  51584
#define FB_BSELF 0
#define FB_BDYN 128
#define FB_LB1 192
#define FB_LB2 256
#define FB_CB1 320
#define FB_CB2 384
#define FB_SU  448   // [g][w][h][f] : 36
#define FB_AO  484   // [g][w][64]   : 256
#define FS_TOT 740

union U4 { uint4 q; h2 p[8]; };
union U1 { uint u; h2 h; };

__device__ __forceinline__ float fd(h2 a, h2 b, float c){
#if __has_builtin(__builtin_amdgcn_fdot2)
  return __builtin_amdgcn_fdot2(a,b,c,false);
#else
  return c + (float)a.x*(float)b.x + (float)a.y*(float)b.y;
#endif
}
__device__ __forceinline__ float lrelu(float x,float s){ return x>=0.f? x : s*x; }
// ELU: every consumer rounds to fp16, so exp(x)-1 (abs err ~1e-7) == expm1f at fp16
// granularity; __expf is a single v_exp_f32 vs the ~25-inst expm1f polynomial.
__device__ __forceinline__ float eluf(float x){ return x>0.f? x : __expf(x)-1.f; }
__device__ __forceinline__ uint packh2(float a,float b){ U1 u; u.h=(h2){(_Float16)a,(_Float16)b}; return u.u; }

__device__ __forceinline__ int span_to_comb(int sp){
  switch(sp){ case 228: return 256; case 229: return 257; case 230: return 260; case 231: return 261;
    case 232: return 264; case 233: return 265; case 247: return 258; case 248: return 259;
    case 249: return 262; case 250: return 263; case 251: return 267; case 252: return 268;
    case 253: return 266; default: return -1; }
}

// ======================= prologue: weight repack fp32 -> fp16 blob (single kernel) =======================
__global__ void k_prep_all(const float* __restrict__ Wself, const float* __restrict__ Wdyn,
                       const float* __restrict__ lW1, const float* __restrict__ lW2,
                       const float* __restrict__ hWh, const float* __restrict__ cWh,
                       const float* __restrict__ hWo, const float* __restrict__ cWo,
                       const float* __restrict__ ha1, const float* __restrict__ ha2,
                       const float* __restrict__ ca1, const float* __restrict__ ca2,
                       const float* __restrict__ hao1, const float* __restrict__ hao2,
                       const float* __restrict__ cao1, const float* __restrict__ cao2,
                       const float* __restrict__ bself, const float* __restrict__ bdyn,
                       const float* __restrict__ lb1, const float* __restrict__ lb2,
                       const float* __restrict__ cb1, const float* __restrict__ cb2,
                       const float* __restrict__ cmW1, const float* __restrict__ cmW2,
                       _Float16* __restrict__ wt)
{
  int gid = blockIdx.x*blockDim.x + threadIdx.x;
  int nth = gridDim.x*blockDim.x;
  for (int idx = gid; idx < WT_F16; idx += nth){
    float v = 0.f;
    if (idx < OFF_DYN){ int l=idx; int j=l/24, k=l%24;
      if (k<16){ int s=k>>2, c=k&3; if (c<3) v = Wself[(s*3+c)*128 + j]; }
      else { int sp = 232 + (k-16); if (sp>=234 && sp<=236) v = Wself[(12+(sp-234))*128 + j]; }
    } else if (idx < OFF_L1){ int l=idx-OFF_DYN; int j=l>>7, k=l&127; v = Wdyn[k*64+j]; }
    else if (idx < OFF_L2){ int l=idx-OFF_L1; int j=l/112, k=l%112; if (k<108) v = lW1[k*64+j]; }
    else if (idx < OFF_WHX){ int l=idx-OFF_L2; int j=l>>6, k=l&63; v = lW2[k*64+j]; }
    else if (idx < OFF_WO){ int l=idx-OFF_WHX; int g=l/192; l-=g*192; int j=l>>2, k=l&3;
      const float* Wh = g? cWh : hWh; int hh=j>>4, o=j&15; if (k<3) v = Wh[hh*48 + k*16 + o]; }
    else if (idx < OFF_W1){ int l=idx-OFF_WO; int g=l/3072; l-=g*3072; int j=l/48, k=l%48;
      const float* Wo = g? cWo : hWo; v = Wo[k*64+j]; }
    else if (idx < OFF_W2){ int l=idx-OFF_W1; int j=l/288, k=l%288;
      int r = (k<256) ? k : span_to_comb(224 + (k-256));
      if (r>=0) v = cmW1[r*64 + j];
    } else { int l=idx-OFF_W2; int j=l>>6, k=l&63; v = cmW2[k*64+j]; }
    wt[idx] = (_Float16)v;
  }
  float* fso = (float*)(wt + WT_F16);
  for (int i = gid; i < FS_TOT; i += nth){
    float v=0.f;
    if (i<128) v = bself[i];
    else if (i<192) v = bdyn[i-128];
    else if (i<256) v = lb1[i-192];
    else if (i<320) v = lb2[i-256];
    else if (i<384) v = cb1[i-320];
    else if (i<448) v = cb2[i-384];
    else if (i<484){ int t=i-448; int g=t/18, w=(t%18)/9, hh=(t%9)/3, f=t%3;
      const float* A = g? (w? ca2:ca1) : (w? ha2:ha1);
      const float* WH = g? cWh : hWh; v=0.f;
      for (int o=0;o<16;++o) v += WH[hh*48+f*16+o]*A[hh*16+o]; }
    else { int t=i-484; int g=t>>7, w=(t>>6)&1, j=t&63;
      const float* A = g? (w?cao2:cao1) : (w?hao2:hao1); v = A[j]; }
    fso[i]=v;
  }
}

// ======================= gpass helpers (8 wave-uniform cols) =======================
__device__ __forceinline__ float dot8u(uint a,uint b,uint c,uint d, const U4& q, float t){
  U1 u; u.u=a; t=fd(u.h,q.p[0],t); u.u=b; t=fd(u.h,q.p[1],t);
  u.u=c; t=fd(u.h,q.p[2],t); u.u=d; t=fd(u.h,q.p[3],t); return t;
}

// x from transposed LDS: chunk c at xl + c*512 f16 (lane*16B contiguous -> conflict-free)
__device__ __forceinline__ void gpass8(float acc[8], const _Float16* xl,
    const _Float16* __restrict__ wt, long wbase, int KP, int C){
  #pragma unroll 2
  for (int c=0;c<C;++c){
    union{h8 v; uint u[4];} x; x.v = *(const h8*)(xl + (long)c*512);
    #pragma unroll
    for (int j=0;j<8;++j){
      U4 q = *(const U4*)(wt + wbase + (long)j*KP + c*8);
      acc[j] = dot8u(x.u[0],x.u[1],x.u[2],x.u[3],q,acc[j]);
    }
  }
}

__device__ __forceinline__ void put_piece(_Float16* pbase, int wj, int lane, const float* v8){
  uint4 q; q.x=packh2(v8[0],v8[1]); q.y=packh2(v8[2],v8[3]);
  q.z=packh2(v8[4],v8[5]); q.w=packh2(v8[6],v8[7]);
  *(uint4*)(pbase + wj*512 + lane*8) = q;
}

// ======================= GAT phase-1 (per (g,head) wave) =======================
template<int N>
__device__ __forceinline__ void gat_phase1(const float* __restrict__ fs,
    const _Float16* __restrict__ wt, const float* __restrict__ nod,
    int g, int hh, _Float16* scr, int lane)
{
  const int xoff = (N==13)? 0 : 72;
  float u10=fs[FB_SU+g*18+hh*3+0], u11=fs[FB_SU+g*18+hh*3+1], u12=fs[FB_SU+g*18+hh*3+2];
  float u20=fs[FB_SU+g*18+9+hh*3+0], u21=fs[FB_SU+g*18+9+hh*3+1], u22=fs[FB_SU+g*18+9+hh*3+2];
  float px[N], py[N], pz[N];
  px[0]=nod[234]; py[0]=nod[235]; pz[0]=nod[236];
  #pragma unroll
  for (int n=1;n<N;++n){ int b0=xoff+(n-1)*6; px[n]=nod[b0]; py[n]=nod[b0+1]; pz[n]=nod[b0+2]; }
  float sx0=px[0], sy0=py[0], sz0=pz[0];
  float s1v = u10*sx0 + u11*sy0 + u12*sz0;
  float sc[N]; float mx = -1e30f;
  #pragma unroll
  for (int n=0;n<N;++n){
    float ev = lrelu(s1v + u20*px[n] + u21*py[n] + u22*pz[n], 0.2f);
    sc[n]=ev; mx=fmaxf(mx,ev);
  }
  // fused normalize + aggregate: accumulate unnormalized, scale once
  float sum=0.f, g0=0.f, g1=0.f, g2=0.f;
  #pragma unroll
  for (int n=0;n<N;++n){
    float w=__expf(sc[n]-mx); sum+=w;
    g0 += w*px[n]; g1 += w*py[n]; g2 += w*pz[n];
  }
  float inv = 1.f/sum; g0*=inv; g1*=inv; g2*=inv;
  // x20/x2X outputs for this head: cols hh*16..hh*16+15
  const _Float16* wh = wt + OFF_WHX + g*192 + (hh*16)*4;
  uint o20[8], o2X[8];
  #pragma unroll
  for (int t=0;t<8;++t){
    float wa0=(float)wh[(2*t)*4],   wa1=(float)wh[(2*t)*4+1],   wa2=(float)wh[(2*t)*4+2];
    float wb0=(float)wh[(2*t+1)*4], wb1=(float)wh[(2*t+1)*4+1], wb2=(float)wh[(2*t+1)*4+2];
    float v0 = eluf(g0*wa0 + g1*wa1 + g2*wa2);
    float v1 = eluf(g0*wb0 + g1*wb1 + g2*wb2);
    float xv0= eluf(sx0*wa0 + sy0*wa1 + sz0*wa2);
    float xv1= eluf(sx0*wb0 + sy0*wb1 + sz0*wb2);
    o20[t]=packh2(v0,v1); o2X[t]=packh2(xv0,xv1);
  }
  int c20 = (g*2)*6 + 2*hh, c2X = (g*2+1)*6 + 2*hh;
  *(uint4*)(scr + (long)c20*512 + lane*8)     = make_uint4(o20[0],o20[1],o20[2],o20[3]);
  *(uint4*)(scr + (long)(c20+1)*512 + lane*8) = make_uint4(o20[4],o20[5],o20[6],o20[7]);
  *(uint4*)(scr + (long)c2X*512 + lane*8)     = make_uint4(o2X[0],o2X[1],o2X[2],o2X[3]);
  *(uint4*)(scr + (long)(c2X+1)*512 + lane*8) = make_uint4(o2X[4],o2X[5],o2X[6],o2X[7]);
}

// ======================= main fused kernel =======================
// 512 thr = 8 waves; wave wj owns cols [8wj,8wj+8); lane = example (64/block).
__global__ __launch_bounds__(512,4) void k_main(const float* __restrict__ obs,
    const _Float16* __restrict__ wt, float* __restrict__ out, int Bn)
{
  __shared__ __align__(16) unsigned char smem[60416];
  _Float16* slt = (_Float16*)smem;              // 17 chunks: span f16 pos [120..256)
  _Float16* scr = (_Float16*)(smem + 17408);    // 24 chunks: x128 exchange / GAT x20,x2X
  float*    pp  = (float*)(smem + 41984);       // [8 wave][64 lane][5] f32 (stride-5: conflict-free)
  _Float16* pbx = (_Float16*)(smem + 52224);    // 8 chunks: 64-col piece exchange

  const float* fs = (const float*)(wt + WT_F16);
  int wj   = __builtin_amdgcn_readfirstlane((int)(threadIdx.x >> 6));
  int lane = threadIdx.x & 63;
  int jb   = 8*wj;
  int e0   = blockIdx.x*64;
  int ge   = e0 + lane; int gec = ge < Bn ? ge : Bn-1;
  const float* nod   = obs + (long)gec*ROW + 5*OS;
  const float* myrow = obs + (long)gec*ROW;

  // ---- hist scattered loads issued FIRST so their HBM latency overlaps staging ----
  float2 ha[4], hb[4];
  #pragma unroll
  for (int s=0;s<4;++s){
    ha[s] = *(const float2*)(myrow + (s+1)*OS + 234);
    hb[s] = *(const float2*)(myrow + (s+1)*OS + 236);
  }

  // ---- stage span [5OS, 5OS+256) into transposed LDS (coalesced; also prefetches
  //      the whole current-step region that GAT phase-1 reads later) ----
  #pragma unroll
  for (int t=wj; t<64; t+=8){
    int gx = e0 + t; if (gx >= Bn) gx = Bn-1;
    float4 v = *(const float4*)(obs + (long)gx*ROW + 5*OS + 4*lane);
    if (lane >= 30){
      uint2 w; w.x = packh2(v.x,v.y); w.y = packh2(v.z,v.w);
      *(uint2*)(slt + (long)((lane>>1)-15)*512 + t*8 + (lane&1)*4) = w;
    }
  }
  uint xe[12];
  #pragma unroll
  for (int s=0;s<4;++s){ xe[2*s]=packh2(ha[s].x,ha[s].y); xe[2*s+1]=packh2(hb[s].x,hb[s].y); }
  __syncthreads();                                              // S1
  { union{h8 v; uint u[4];} t29; t29.v = *(const h8*)(slt + 14*512 + lane*8);  // span[232..240)
    xe[8]=t29.u[0]; xe[9]=t29.u[1]; xe[10]=t29.u[2]; xe[11]=t29.u[3]; }

  // ---- ego: [24]->[128], double leaky(0.1); 16 cols/wave in 2 passes ----
  {
    uint own[8];
    #pragma unroll
    for (int p=0;p<2;++p){
      float acc[8]; int cb = 16*wj + 8*p;
      #pragma unroll
      for (int j=0;j<8;++j) acc[j] = fs[FB_BSELF + cb + j];
      #pragma unroll
      for (int c=0;c<3;++c){
        uint a=xe[4*c], b=xe[4*c+1], cc2=xe[4*c+2], d=xe[4*c+3];
        #pragma unroll
        for (int j=0;j<8;++j){
          U4 q = *(const U4*)(wt + OFF_EGO + (long)(cb+j)*24 + c*8);
          acc[j] = dot8u(a,b,cc2,d,q,acc[j]);
        }
      }
      #pragma unroll
      for (int t=0;t<4;++t){
        float a=acc[2*t], b=acc[2*t+1];
        a = a>=0.f? a : 0.01f*a;  b = b>=0.f? b : 0.01f*b;
        own[4*p+t] = packh2(a,b);
      }
    }
    *(uint4*)(scr + (long)(2*wj)*512 + lane*8)   = make_uint4(own[0],own[1],own[2],own[3]);
    *(uint4*)(scr + (long)(2*wj+1)*512 + lane*8) = make_uint4(own[4],own[5],own[6],own[7]);
  }
  __syncthreads();                                              // S2

  // ---- dyn: [128]->[64] ----
  float accW1[8];
  {
    float ef[8];
    #pragma unroll
    for (int j=0;j<8;++j) ef[j] = fs[FB_BDYN + jb + j];
    gpass8(ef, scr + lane*8, wt, OFF_DYN + (long)jb*128, 128, 16);
    // no barrier needed: pbx is disjoint from scr; S4 below fences the pbx writes
    put_piece(pbx, wj, lane, ef);
  }
  __syncthreads();                                              // S4
  #pragma unroll
  for (int j=0;j<8;++j) accW1[j] = fs[FB_CB1 + jb + j];
  gpass8(accW1, pbx + lane*8, wt, OFF_W1 + (long)jb*288, 288, 8);
  __syncthreads();                                              // S5

  // ---- lane MLP: [108(pad112)]->[64] relu -> [64]->[64] relu ----
  {
    float l1[8];
    #pragma unroll
    for (int j=0;j<8;++j) l1[j] = fs[FB_LB1 + jb + j];
    gpass8(l1, slt + lane*8, wt, OFF_L1 + (long)jb*112, 112, 14);
    #pragma unroll
    for (int j=0;j<8;++j) l1[j] = fmaxf(l1[j],0.f);
    put_piece(pbx, wj, lane, l1);
  }
  __syncthreads();                                              // S6
  {
    float l2[8];
    #pragma unroll
    for (int j=0;j<8;++j) l2[j] = fs[FB_LB2 + jb + j];
    gpass8(l2, pbx + lane*8, wt, OFF_L2 + (long)jb*64, 64, 8);
    __syncthreads();                                            // S7 (WAR on pbx)
    #pragma unroll
    for (int j=0;j<8;++j) l2[j] = fmaxf(l2[j],0.f);
    put_piece(pbx, wj, lane, l2);
  }
  __syncthreads();                                              // S8
  gpass8(accW1, pbx + lane*8, wt, OFF_W1 + (long)jb*288 + 192, 288, 8);
  // no barrier needed: gat writes scr (disjoint from pbx); scr's last readers were
  // fenced at S4..S8; S10 below fences the scr writes before the WO reads.

  // ---- GAT phase-1: one wave per (g,head); waves 3,7 idle ----
  if (wj < 3)             gat_phase1<13>(fs, wt, nod, 0, wj,   scr, lane);
  else if (wj>=4 && wj<7) gat_phase1<9> (fs, wt, nod, 1, wj-4, scr, lane);
  __syncthreads();                                              // S10

  // ---- GAT WO + attention-2 + W1 blocks ----
  for (int g=0; g<2; ++g){
    const int N = g? 9 : 13;
    float a0[8], aX[8];
    #pragma unroll
    for (int j=0;j<8;++j){ a0[j]=0.f; aX[j]=0.f; }
    long wb = OFF_WO + g*3072 + (long)jb*48;
    #pragma unroll 2
    for (int c=0;c<6;++c){
      union{h8 v; uint u[4];} x0, x1;
      x0.v = *(const h8*)(scr + (long)((g*2)*6+c)*512 + lane*8);
      x1.v = *(const h8*)(scr + (long)((g*2+1)*6+c)*512 + lane*8);
      #pragma unroll
      for (int j=0;j<8;++j){
        U4 q = *(const U4*)(wt + wb + (long)j*48 + c*8);
        a0[j] = dot8u(x0.u[0],x0.u[1],x0.u[2],x0.u[3],q,a0[j]);
        aX[j] = dot8u(x1.u[0],x1.u[1],x1.u[2],x1.u[3],q,aX[j]);
      }
    }
    float p1=0.f,p2=0.f,p3=0.f;
    #pragma unroll
    for (int j=0;j<8;++j){
      float w1v=fs[FB_AO + g*128 + jb + j], w2v=fs[FB_AO + g*128 + 64 + jb + j];
      p1 += a0[j]*w1v; p2 += a0[j]*w2v; p3 += aX[j]*w2v;
    }
    { float* pr = pp + (long)(wj*64+lane)*5; pr[0]=p1; pr[1]=p2; pr[2]=p3; }
    __syncthreads();                                            // S11/S14
    float q1=0.f,q2=0.f,q3=0.f;
    #pragma unroll
    for (int w=0;w<8;++w){ const float* pr = pp + (long)(w*64+lane)*5;
      q1+=pr[0]; q2+=pr[1]; q3+=pr[2]; }
    float e00=lrelu(q1+q2,0.2f), e0X=lrelu(q1+q3,0.2f);
    float mm=fmaxf(e00,e0X);
    float w0=__expf(e00-mm), wX=__expf(e0X-mm);
    float invden = 1.f/(w0 + (float)(N-1)*wX);
    float kX = (float)(N-1)*wX*invden; w0 *= invden;
    float og[8];
    #pragma unroll
    for (int j=0;j<8;++j) og[j] = eluf(w0*a0[j] + kX*aX[j]);
    put_piece(pbx, wj, lane, og);
    __syncthreads();                                            // S12/S15
    gpass8(accW1, pbx + lane*8, wt, OFF_W1 + (long)jb*288 + 64 + 64*g, 288, 8);
    __syncthreads();                                            // S13/S16
  }

  // ---- comb span block: span[224..256) = slt chunks 13..16, W1 k256..287 ----
  gpass8(accW1, slt + 13*512 + lane*8, wt, OFF_W1 + (long)jb*288 + 256, 288, 4);

  // ---- relu -> chid piece -> W2 -> relu -> store ----
  {
    float ch[8];
    #pragma unroll
    for (int j=0;j<8;++j) ch[j] = fmaxf(accW1[j],0.f);
    put_piece(pbx, wj, lane, ch);
  }
  __syncthreads();                                              // S17
  {
    float o[8];
    #pragma unroll
    for (int j=0;j<8;++j) o[j] = fs[FB_CB2 + jb + j];
    gpass8(o, pbx + lane*8, wt, OFF_W2 + (long)jb*64, 64, 8);
    if (ge < Bn){
      float4 v0, v1;
      v0.x=fmaxf(o[0],0.f); v0.y=fmaxf(o[1],0.f); v0.z=fmaxf(o[2],0.f); v0.w=fmaxf(o[3],0.f);
      v1.x=fmaxf(o[4],0.f); v1.y=fmaxf(o[5],0.f); v1.z=fmaxf(o[6],0.f); v1.w=fmaxf(o[7],0.f);
      *(float4*)(out + (long)ge*64 + jb)     = v0;
      *(float4*)(out + (long)ge*64 + jb + 4) = v1;
    }
  }
}

extern "C" void kernel_launch(void* const* d_in, const int* in_sizes, int n_in,
                              void* d_out, int out_size, void* d_ws, size_t ws_size,
                              hipStream_t stream)
{
  const float* obs  =(const float*)d_in[0];
  const float* Wself=(const float*)d_in[1];  const float* bself=(const float*)d_in[2];
  const float* Wdyn =(const float*)d_in[3];  const float* bdyn =(const float*)d_in[4];
  const float* hWh  =(const float*)d_in[5];  const float* ha1  =(const float*)d_in[6];
  const float* ha2  =(const float*)d_in[7];  const float* hWo  =(const float*)d_in[8];
  const float* hao1 =(const float*)d_in[9];  const float* hao2 =(const float*)d_in[10];
  const float* cWh  =(const float*)d_in[11]; const float* ca1  =(const float*)d_in[12];
  const float* ca2  =(const float*)d_in[13]; const float* cWo  =(const float*)d_in[14];
  const float* cao1 =(const float*)d_in[15]; const float* cao2 =(const float*)d_in[16];
  const float* lW1  =(const float*)d_in[17]; const float* lb1  =(const float*)d_in[18];
  const float* lW2  =(const float*)d_in[19]; const float* lb2  =(const float*)d_in[20];
  const float* cmW1 =(const float*)d_in[21]; const float* cmb1 =(const float*)d_in[22];
  const float* cmW2 =(const float*)d_in[23]; const float* cmb2 =(const float*)d_in[24];

  int Bn = in_sizes[0] / ROW;
  _Float16* wt = (_Float16*)d_ws;
  float* out = (float*)d_out;

  k_prep_all<<<128,256,0,stream>>>(Wself,Wdyn,lW1,lW2,hWh,cWh,hWo,cWo,ha1,ha2,ca1,ca2,
                                   hao1,hao2,cao1,cao2,bself,bdyn,lb1,lb2,cmb1,cmb2,
                                   cmW1,cmW2,wt);
  int blocks = (Bn + 63)/64;
  k_main<<<blocks,512,0,stream>>>(obs,wt,out,Bn);
}